// Round 3
// baseline (412.690 us; speedup 1.0000x reference)
//
#include <hip/hip_runtime.h>
#include <math.h>

// EfficientDet postprocess for MI355X — round 9.
// R8's single-wave k_nms_t1/k_final were sound but the LAUNCHER still passed
// dim3(256) to k_final (__launch_bounds__(64)) -> invalid config -> k_final
// never ran -> zeroed outputs (out_c absmax 89 signature). This round is R8
// with the one-line launch fix: k_final<<<NB, 64>>>.
//   k_nms_t1: 64 threads (1 wave: s_barrier immediate). Same algorithm/order;
//     alive flags in per-lane register bitmask (t = tid + 64q); dead
//     iterations eliminated via next-alive shfl_xor min-reduce; adaptive
//     sort size (128/256/512 by M).
//   k_final: 64 threads, frontier ptrs in registers (classes tid, tid+64),
//     winner via shfl_xor max butterfly.
// k_anchors/k_decode/k_scan/k_nms_fb verbatim from R7 (passing build).

#define NANCH 49104
#define NB 8
#define NC 90
#define NBC 720
#define POSTN 100
#define T1CAP 512
#define CHUNK 512
#define NCH 96          // ceil(49104/512)
#define LCAP 32         // per-(class,chunk) LDS list cap
#define EDGE 0.93f      // P(sigmoid(N(0,1)) >= 0.93) ~ 0.484% -> ~238 +/- 15 per (b,c)
#define PRECHK 2.0f     // sigmoid(2.0)=0.8808 < EDGE: safe cheap pre-filter

// ---------- exact-float helpers (mirror numpy f32 semantics, no FMA) ----------

__device__ __forceinline__ float sigmoid_ref(float x) {
  if (x >= 0.0f) return __fdiv_rn(1.0f, __fadd_rn(1.0f, expf(-x)));
  float e = expf(x);
  return __fdiv_rn(e, __fadd_rn(1.0f, e));
}

__device__ __forceinline__ float iou_ref(float4 a, float4 b) {
  float yy1 = fmaxf(a.x, b.x);
  float xx1 = fmaxf(a.y, b.y);
  float yy2 = fminf(a.z, b.z);
  float xx2 = fminf(a.w, b.w);
  float ih = fmaxf(__fsub_rn(yy2, yy1), 0.0f);
  float iw = fmaxf(__fsub_rn(xx2, xx1), 0.0f);
  float inter = __fmul_rn(ih, iw);
  float a1 = __fmul_rn(__fsub_rn(a.z, a.x), __fsub_rn(a.w, a.y));
  float a2 = __fmul_rn(__fsub_rn(b.z, b.x), __fsub_rn(b.w, b.y));
  float den = __fadd_rn(__fsub_rn(__fadd_rn(a1, a2), inter), 1e-8f);
  return __fdiv_rn(inter, den);
}

// ---------------------------- anchors (+ counter zeroing) ----------------------

__global__ __launch_bounds__(256) void k_anchors(float4* __restrict__ anchors,
                                                 unsigned int* __restrict__ gcnt,
                                                 unsigned int* __restrict__ oflow) {
  int n = blockIdx.x * 256 + threadIdx.x;
  if (n < NBC) { gcnt[n] = 0u; oflow[n] = 0u; }
  if (n >= NANCH) return;
  int l, off;
  if (n < 36864)      { l = 0; off = 0; }
  else if (n < 46080) { l = 1; off = 36864; }
  else if (n < 48384) { l = 2; off = 46080; }
  else if (n < 48960) { l = 3; off = 48384; }
  else                { l = 4; off = 48960; }
  int stride = 8 << l;
  int feat = 64 >> l;
  int r = n - off;
  int cell = r / 9, a = r - cell * 9;
  int iy = cell / feat, ix = cell - iy * feat;
  int isc = a / 3, ir = a - isc * 3;
  // numpy computes half-sizes in float64, then casts to float32
  double base = exp2((double)isc / 3.0) * (double)stride * 4.0;
  double rt = (ir == 0) ? 1.0 : (ir == 1 ? 0.5 : 2.0);
  double sq = sqrt(rt);
  float hh = (float)(base / sq / 2.0);
  float hw = (float)(base * sq / 2.0);
  float cy = __fmul_rn(__fadd_rn((float)iy, 0.5f), (float)stride);
  float cx = __fmul_rn(__fadd_rn((float)ix, 0.5f), (float)stride);
  anchors[n] = make_float4(__fsub_rn(cy, hh), __fsub_rn(cx, hw),
                           __fadd_rn(cy, hh), __fadd_rn(cx, hw));
}

// ---------------------------- decode -------------------------------------------

__global__ __launch_bounds__(256) void k_decode(const float4* __restrict__ deltas,
                                                const float4* __restrict__ anchors,
                                                float4* __restrict__ boxes) {
  int i = blockIdx.x * 256 + threadIdx.x;
  if (i >= NB * NANCH) return;
  int n = i % NANCH;
  float4 a = anchors[n];
  float4 d = deltas[i];
  float ah = __fsub_rn(a.z, a.x);
  float aw = __fsub_rn(a.w, a.y);
  float acy = __fmul_rn(__fadd_rn(a.x, a.z), 0.5f);
  float acx = __fmul_rn(__fadd_rn(a.y, a.w), 0.5f);
  float cy = __fadd_rn(__fmul_rn(d.x, ah), acy);
  float cx = __fadd_rn(__fmul_rn(d.y, aw), acx);
  float h = __fmul_rn(expf(d.z), ah);
  float w = __fmul_rn(expf(d.w), aw);
  float y1 = __fsub_rn(cy, __fmul_rn(h, 0.5f));
  float x1 = __fsub_rn(cx, __fmul_rn(w, 0.5f));
  float y2 = __fadd_rn(cy, __fmul_rn(h, 0.5f));
  float x2 = __fadd_rn(cx, __fmul_rn(w, 0.5f));
  const float inv = 0.001953125f;  // 1/512, exact
  y1 = fminf(fmaxf(__fmul_rn(y1, inv), 0.0f), 1.0f);
  x1 = fminf(fmaxf(__fmul_rn(x1, inv), 0.0f), 1.0f);
  y2 = fminf(fmaxf(__fmul_rn(y2, inv), 0.0f), 1.0f);
  x2 = fminf(fmaxf(__fmul_rn(x2, inv), 0.0f), 1.0f);
  boxes[i] = make_float4(y1, x1, y2, x2);
}

// ------------- candidate scan: LDS-aggregated, 1 reservation atomic ------------
// (verbatim R7-passing kernel)

__global__ __launch_bounds__(256) void k_scan(const float4* __restrict__ logits4,
                                              unsigned long long* __restrict__ gcand,
                                              unsigned int* __restrict__ gcnt,
                                              unsigned int* __restrict__ oflow) {
  int b = blockIdx.y;
  int ch = blockIdx.x;
  int n0 = ch * CHUNK;
  int rows = min(CHUNK, NANCH - n0);
  const float4* base = logits4 + ((size_t)b * NANCH + n0) * 90 / 4;
  int tot4 = rows * 90 / 4;
  int tid = threadIdx.x;

  __shared__ unsigned long long lc[NC * LCAP];  // 23 KB
  __shared__ unsigned int lcnt[NC];
  for (int c = tid; c < NC; c += 256) lcnt[c] = 0u;
  __syncthreads();

  for (int e4 = tid; e4 < tot4; e4 += 1024) {
    float4 v[4];
#pragma unroll
    for (int k = 0; k < 4; k++) {
      int idx = e4 + k * 256;
      if (idx < tot4) v[k] = base[idx];
    }
#pragma unroll
    for (int k = 0; k < 4; k++) {
      int idx = e4 + k * 256;
      if (idx >= tot4) break;
      float xs[4] = {v[k].x, v[k].y, v[k].z, v[k].w};
#pragma unroll
      for (int j = 0; j < 4; j++) {
        float x = xs[j];
        if (x >= PRECHK) {  // skips sigmoid for ~98% of elements
          float s = sigmoid_ref(x);
          if (s >= EDGE) {
            int e = idx * 4 + j;
            int r = e / 90, c = e - r * 90;
            unsigned int pos = atomicAdd(&lcnt[c], 1u);  // LDS atomic (on-CU)
            if (pos < LCAP) {
              int n = n0 + r;
              lc[c * LCAP + pos] =
                  ((unsigned long long)__float_as_uint(s) << 32) |
                  (unsigned int)(65535 - n);  // u64 desc == score desc, n asc
            }
          }
        }
      }
    }
  }
  __syncthreads();

  // reserve + flush: one global atomic per (class,chunk) with candidates
  if (tid < NC) {
    unsigned int cnt = lcnt[tid];
    int bc = b * NC + tid;
    if (cnt > LCAP) {  // ~1e-16 probability: flag bc for exact fallback
      atomicOr(&oflow[bc], 1u);
      cnt = LCAP;
    }
    if (cnt > 0) {
      unsigned int pos0 = atomicAdd(&gcnt[bc], cnt);
      for (unsigned int k = 0; k < cnt; k++) {
        unsigned int p = pos0 + k;
        if (p < T1CAP) gcand[(size_t)bc * T1CAP + p] = lc[tid * LCAP + k];
      }
    }
  }
}

// -------------------- tier1: sort <=512 candidates + greedy NMS ----------------
// Single-wave (64-thread) wave-synchronous version of the R4-proven algorithm.
// Barriers are immediate (1-wave workgroup); alive flags live in per-lane
// register bitmask with fixed ownership t = tid + 64q; next-alive index found
// via shfl_xor min-reduce (no dead iterations).

__global__ __launch_bounds__(64) void k_nms_t1(
    const unsigned long long* __restrict__ gcand,
    const unsigned int* __restrict__ gcnt, const unsigned int* __restrict__ oflow,
    const float4* __restrict__ boxes, float* __restrict__ sel_s,
    float4* __restrict__ sel_b, int* __restrict__ flags) {
  int bc = blockIdx.x;
  int b = bc / NC;
  int tid = threadIdx.x;

  __shared__ unsigned long long cand[T1CAP];   // 4 KB
  __shared__ float4 cbox[T1CAP];               // 8 KB
  __shared__ float4 s_selbox[POSTN];
  __shared__ float s_sels[POSTN];

  unsigned int cnt = gcnt[bc];
  bool overflow = (cnt > (unsigned)T1CAP) || (oflow[bc] != 0u);
  int M = (int)min(cnt, (unsigned)T1CAP);
  for (int e = tid; e < T1CAP; e += 64)
    cand[e] = (e < M) ? gcand[(size_t)bc * T1CAP + e] : 0ull;
  __syncthreads();

  // bitonic sort descending (key = score desc, tie idx asc via 65535-n packing)
  // adaptive size: zero-padding beyond M means sorting the first SN suffices.
  int SN = (M <= 128) ? 128 : (M <= 256) ? 256 : 512;
  int np = SN >> 1;  // pairs per stage (64..256)
  for (int k = 2; k <= SN; k <<= 1) {
    for (int j = k >> 1; j > 0; j >>= 1) {
      unsigned long long a[4], bb[4];
      int ii[4];
#pragma unroll
      for (int q = 0; q < 4; q++) {
        int t = tid + (q << 6);
        if (t < np) {
          int i = ((t & ~(j - 1)) << 1) | (t & (j - 1));
          ii[q] = i;
          a[q] = cand[i];
          bb[q] = cand[i | j];
        } else {
          ii[q] = -1;
        }
      }
#pragma unroll
      for (int q = 0; q < 4; q++) {
        if (ii[q] >= 0) {
          bool up = ((ii[q] & k) == 0);
          if (up ? (a[q] < bb[q]) : (a[q] > bb[q])) {
            cand[ii[q]] = bb[q];
            cand[ii[q] | j] = a[q];
          }
        }
      }
      __syncthreads();
    }
  }

  // gather boxes; per-lane alive bitmask over owned slots t = tid + 64q
  unsigned int amask = 0u;
#pragma unroll
  for (int q = 0; q < 8; q++) {
    int t = tid + (q << 6);
    if (t < M) {
      int n = 65535 - (int)(cand[t] & 0xFFFFull);
      cbox[t] = boxes[(size_t)b * NANCH + n];
      amask |= (1u << q);
    }
  }
  __syncthreads();

  // serial greedy NMS, wave-synchronous (exact reference order)
  int nsel = 0;
  int i = 0;
  while (i < M && nsel < POSTN) {
    float4 bi = cbox[i];
    float sc = __uint_as_float((unsigned int)(cand[i] >> 32));
    if (!(iou_ref(bi, bi) > 0.5f)) {
      // degenerate zero-area box: never self-suppresses -> reference re-selects
      // it for every remaining step ("sticky" fill)
      if (tid == 0) {
        for (int p = nsel; p < POSTN; p++) { s_selbox[p] = bi; s_sels[p] = sc; }
      }
      nsel = POSTN;
      break;
    }
    if (tid == 0) { s_selbox[nsel] = bi; s_sels[nsel] = sc; }
    nsel++;
    // sweep owned elems with t > i; suppress and find next alive
    int nxt = M;
#pragma unroll
    for (int q = 0; q < 8; q++) {
      int t = tid + (q << 6);
      if (((amask >> q) & 1u) && t > i) {
        if (iou_ref(cbox[t], bi) > 0.5f) amask &= ~(1u << q);
        else nxt = min(nxt, t);
      }
    }
#pragma unroll
    for (int d = 1; d < 64; d <<= 1) {
      int o = __shfl_xor(nxt, d, 64);
      nxt = min(nxt, o);
    }
    i = nxt;
  }
  __syncthreads();

  // valid only if 100 selections completed from a complete (non-overflowed) list
  bool bad = overflow || (nsel < POSTN);
  if (tid == 0) flags[bc] = bad ? 1 : 0;
  if (bad) return;
  for (int p = tid; p < POSTN; p += 64) {
    float s0 = s_sels[p];
    bool valid = (s0 > 0.2f);  // SCORE_THR gate (always true here: s0>=EDGE)
    sel_s[bc * POSTN + p] = valid ? s0 : 0.0f;
    sel_b[bc * POSTN + p] = valid ? s_selbox[p] : make_float4(0, 0, 0, 0);
  }
}

// -------- flag-all helper (only if workspace too small for scan buffers) -------

__global__ __launch_bounds__(256) void k_flagall(int* __restrict__ flags) {
  int i = blockIdx.x * 256 + threadIdx.x;
  if (i < NBC) flags[i] = 1;
}

// -------- exact fallback: histogram rank-5000 + sort + NMS (rare/never) --------

template <int CAP, int RANK>
__global__ __launch_bounds__(256) void k_nms_fb(const float* __restrict__ logits,
                                                const float4* __restrict__ boxes,
                                                float* __restrict__ sel_s,
                                                float4* __restrict__ sel_b,
                                                const int* __restrict__ flags) {
  int bc = blockIdx.x;
  if (flags[bc] == 0) return;
  int b = bc / NC;
  int c = bc - b * NC;
  int tid = threadIdx.x;

  __shared__ unsigned int s_key[CAP];
  __shared__ unsigned short s_idx[CAP];
  __shared__ __align__(16) unsigned char s_pool[8192];
  __shared__ unsigned int s_bsum[256];
  __shared__ unsigned char s_alive[512];
  __shared__ float4 s_selbox[POSTN];
  __shared__ float s_sels[POSTN];
  __shared__ int s_cnt, s_nsel, s_cutbin;

  const float* lrow = logits + (size_t)b * NANCH * 90 + c;

  unsigned int* hist = (unsigned int*)s_pool;
  for (int e = tid; e < 2048; e += 256) hist[e] = 0u;
  if (tid == 0) { s_cnt = 0; s_nsel = 0; s_cutbin = 0; }
  __syncthreads();

  for (int n = tid; n < NANCH; n += 256) {
    float s = sigmoid_ref(lrow[(size_t)n * 90]);
    int bin = (int)(s * 2048.0f);
    if (bin > 2047) bin = 2047;
    atomicAdd(&hist[bin], 1u);
  }
  __syncthreads();
  unsigned int loc = 0;
#pragma unroll
  for (int k = 0; k < 8; k++) loc += hist[tid * 8 + k];
  s_bsum[tid] = loc;
  __syncthreads();
  if (tid == 0) {
    unsigned int cum = 0;
    int bin = 0;
    bool fnd = false;
    for (int t = 255; t >= 0 && !fnd; t--) {
      if (cum + s_bsum[t] >= (unsigned)RANK) {
        for (int kk = 7; kk >= 0; kk--) {
          unsigned int h = hist[t * 8 + kk];
          if (cum + h >= (unsigned)RANK) { bin = t * 8 + kk; fnd = true; break; }
          cum += h;
        }
      } else {
        cum += s_bsum[t];
      }
    }
    s_cutbin = bin;
  }
  __syncthreads();
  float edge = __fmul_rn((float)s_cutbin, (1.0f / 2048.0f));  // exact

  for (int n = tid; n < NANCH; n += 256) {
    float s = sigmoid_ref(lrow[(size_t)n * 90]);
    if (s >= edge) {
      int pos = atomicAdd(&s_cnt, 1);
      if (pos < CAP) {
        s_key[pos] = __float_as_uint(s);
        s_idx[pos] = (unsigned short)n;
      }
    }
  }
  __syncthreads();
  int M = s_cnt;
  if (M > CAP) M = CAP;
  for (int e = M + tid; e < CAP; e += 256) { s_key[e] = 0u; s_idx[e] = 0xFFFFu; }
  __syncthreads();

  for (int k = 2; k <= CAP; k <<= 1) {
    for (int j = k >> 1; j > 0; j >>= 1) {
      for (int t = tid; t < CAP / 2; t += 256) {
        int i = ((t & ~(j - 1)) << 1) | (t & (j - 1));
        int p = i | j;
        unsigned int ka = s_key[i], kb = s_key[p];
        unsigned short ia = s_idx[i], ib = s_idx[p];
        bool up = ((i & k) == 0);
        bool g = (ka < kb) || (ka == kb && ia > ib);
        bool l = (kb < ka) || (ka == kb && ib > ia);
        if (up ? g : l) {
          s_key[i] = kb; s_key[p] = ka;
          s_idx[i] = ib; s_idx[p] = ia;
        }
      }
      __syncthreads();
    }
  }

  float4* cbox = (float4*)s_pool;
  int L = (M < 5000) ? M : 5000;  // PRE_NMS truncation (stable)
  for (int base = 0; base < L; base += 512) {
    int cn = min(512, L - base);
    int ns0 = s_nsel;
    if (ns0 >= POSTN) break;
    for (int t = tid; t < cn; t += 256) {
      int n = s_idx[base + t];
      float4 bx = boxes[(size_t)b * NANCH + n];
      bool al = true;
      for (int s = 0; s < ns0; s++) {
        if (iou_ref(bx, s_selbox[s]) > 0.5f) { al = false; break; }
      }
      cbox[t] = bx;
      s_alive[t] = al ? 1 : 0;
    }
    __syncthreads();
    for (int i = 0; i < cn; i++) {
      if (s_nsel >= POSTN) break;
      if (!s_alive[i]) continue;
      float4 bi = cbox[i];
      float sc = __uint_as_float(s_key[base + i]);
      if (!(iou_ref(bi, bi) > 0.5f)) {
        if (tid == 0) {
          for (int p = s_nsel; p < POSTN; p++) { s_selbox[p] = bi; s_sels[p] = sc; }
          s_nsel = POSTN;
        }
        __syncthreads();
        break;
      }
      for (int t = tid; t < cn; t += 256) {
        if (t > i && s_alive[t] && iou_ref(cbox[t], bi) > 0.5f) s_alive[t] = 0;
      }
      if (tid == 0) {
        s_selbox[s_nsel] = bi;
        s_sels[s_nsel] = sc;
        s_nsel = s_nsel + 1;
      }
      __syncthreads();
    }
    __syncthreads();
    if (s_nsel >= POSTN) break;
  }
  __syncthreads();
  int ns = s_nsel;
  for (int p = tid; p < POSTN; p += 256) {
    float sc = 0.0f;
    float4 bx = make_float4(0.0f, 0.0f, 0.0f, 0.0f);
    if (p < ns) {
      float s0 = s_sels[p];
      if (s0 > 0.2f) { sc = s0; bx = s_selbox[p]; }
    }
    sel_s[bc * POSTN + p] = sc;
    sel_b[bc * POSTN + p] = bx;
  }
}

// ---------------- per-batch top-100: frontier merge, single-wave ----------------
// Per-class sel_s rows are non-increasing. Stable top-100 == 100 steps of a
// stable 90-way frontier max. Lane l owns classes l and l+64; frontier
// pointers live in registers; winner via shfl_xor max butterfly (no barriers).

__global__ __launch_bounds__(64) void k_final(const float* __restrict__ sel_s,
                                              const float4* __restrict__ sel_b,
                                              float* __restrict__ out) {
  int b = blockIdx.x;
  int tid = threadIdx.x;
  __shared__ float key[9000];
  __shared__ unsigned int win_k[POSTN];
  __shared__ int win_e[POSTN];
  for (int e = tid; e < 9000; e += 64) key[e] = sel_s[(size_t)b * 9000 + e];
  int p0 = 0, p1 = 0;       // frontier ptrs for classes tid and tid+64
  int c1 = tid + 64;        // valid iff c1 < NC (lanes 0..25)
  __syncthreads();
  for (int p = 0; p < POSTN; p++) {
    unsigned long long v = 0ull;
    if (p0 < POSTN) {
      int e = tid * POSTN + p0;
      v = ((unsigned long long)__float_as_uint(key[e]) << 32) |
          (unsigned int)(16383 - e);  // max score, then min flat idx (stable)
    }
    if (c1 < NC && p1 < POSTN) {
      int e = c1 * POSTN + p1;
      unsigned long long v2 = ((unsigned long long)__float_as_uint(key[e]) << 32) |
                              (unsigned int)(16383 - e);
      if (v2 > v) v = v2;
    }
#pragma unroll
    for (int d = 1; d < 64; d <<= 1) {
      unsigned long long o = __shfl_xor(v, d, 64);
      if (o > v) v = o;
    }
    int e = 16383 - (int)(v & 0x3FFFull);
    if (tid == 0) { win_k[p] = (unsigned int)(v >> 32); win_e[p] = e; }
    int cls = e / POSTN;
    int pp = e - cls * POSTN;
    if (cls == tid) p0 = pp + 1;
    else if (cls == c1) p1 = pp + 1;
  }
  __syncthreads();
  for (int p = tid; p < POSTN; p += 64) {
    unsigned int k = win_k[p];
    int e = win_e[p];
    float4 bx = sel_b[(size_t)b * 9000 + e];
    ((float4*)out)[b * POSTN + p] = bx;              // out_b [8,100,4]
    out[3200 + b * POSTN + p] = __uint_as_float(k);  // out_s [8,100]
    out[4000 + b * POSTN + p] = (float)(e / POSTN);  // out_c [8,100]
  }
  int vcnt = 0;
  for (int p = tid; p < POSTN; p += 64) vcnt += (win_k[p] != 0u) ? 1 : 0;
#pragma unroll
  for (int d = 1; d < 64; d <<= 1) vcnt += __shfl_xor(vcnt, d, 64);
  if (tid == 0) out[4800 + b] = (float)vcnt;  // valid [8]
}

// ------------------------------- launcher --------------------------------------

extern "C" void kernel_launch(void* const* d_in, const int* in_sizes, int n_in,
                              void* d_out, int out_size, void* d_ws, size_t ws_size,
                              hipStream_t stream) {
  const float* deltas = (const float*)d_in[0];  // [8,49104,4]
  const float* logits = (const float*)d_in[1];  // [8,49104,90]
  float* out = (float*)d_out;
  char* ws = (char*)d_ws;

  size_t off = 0;
  auto take = [&](size_t bytes) -> char* {
    char* p = ws + off;
    off += (bytes + 255) & ~(size_t)255;
    return p;
  };
  // small/required buffers first so the degraded path fits in ~8.6 MB
  float4* anchors = (float4*)take((size_t)NANCH * 16);
  float4* boxes = (float4*)take((size_t)NB * NANCH * 16);
  float* sel_s = (float*)take((size_t)NBC * POSTN * 4);
  float4* sel_b = (float4*)take((size_t)NBC * POSTN * 16);
  int* flags = (int*)take((size_t)NBC * 4);
  unsigned int* gcnt = (unsigned int*)take((size_t)NBC * 4);
  unsigned int* oflow = (unsigned int*)take((size_t)NBC * 4);
  unsigned long long* gcand =
      (unsigned long long*)take((size_t)NBC * T1CAP * 8);
  bool fits = (off <= ws_size);  // total ~11.5 MB

  k_anchors<<<dim3((NANCH + 255) / 256), dim3(256), 0, stream>>>(anchors, gcnt,
                                                                 oflow);
  k_decode<<<dim3((NB * NANCH + 255) / 256), dim3(256), 0, stream>>>(
      (const float4*)deltas, anchors, boxes);
  if (fits) {
    k_scan<<<dim3(NCH, NB), dim3(256), 0, stream>>>((const float4*)logits,
                                                    gcand, gcnt, oflow);
    k_nms_t1<<<dim3(NBC), dim3(64), 0, stream>>>(gcand, gcnt, oflow, boxes,
                                                 sel_s, sel_b, flags);
  } else {
    k_flagall<<<dim3((NBC + 255) / 256), dim3(256), 0, stream>>>(flags);
  }
  k_nms_fb<8192, 5000><<<dim3(NBC), dim3(256), 0, stream>>>(logits, boxes,
                                                            sel_s, sel_b, flags);
  k_final<<<dim3(NB), dim3(64), 0, stream>>>(sel_s, sel_b, out);
}

// Round 4
// 406.971 us; speedup vs baseline: 1.0141x; 1.0141x over previous
//
#include <hip/hip_runtime.h>
#include <math.h>

// EfficientDet postprocess for MI355X — round 10.
// R9 passed but t1 regressed to 150 us: 720 single-wave blocks = 0.7 wave/SIMD
// (no latency hiding) and the sweep re-read cbox[t] from LDS per-q per-iter
// under divergent predicates (~8 serialized ds_read round-trips/iter) plus a
// 6-deep shfl_xor next-alive chain. Fix = shorten the chain, not add waves:
//   - boxes held in 8 float4 REGISTERS per lane (loaded once post-sort);
//     suppress sweep is pure VALU, zero LDS in the loop body.
//   - next-alive via 8x __ballot (SGPR masks) + wave-uniform scalar
//     __ffsll find; no dependent shuffle chain.
//   - selected box broadcast = single uniform LDS read (cbox[i], cand[i]).
// Sort/load/epilogue and all other kernels verbatim from R9 (passing build,
// k_final launched at 64 threads). NMS semantics unchanged (suppress-then-
// find-next, sticky degenerate fill, overflow/starvation -> exact fallback).

#define NANCH 49104
#define NB 8
#define NC 90
#define NBC 720
#define POSTN 100
#define T1CAP 512
#define CHUNK 512
#define NCH 96          // ceil(49104/512)
#define LCAP 32         // per-(class,chunk) LDS list cap
#define EDGE 0.93f      // P(sigmoid(N(0,1)) >= 0.93) ~ 0.484% -> ~238 +/- 15 per (b,c)
#define PRECHK 2.0f     // sigmoid(2.0)=0.8808 < EDGE: safe cheap pre-filter

// ---------- exact-float helpers (mirror numpy f32 semantics, no FMA) ----------

__device__ __forceinline__ float sigmoid_ref(float x) {
  if (x >= 0.0f) return __fdiv_rn(1.0f, __fadd_rn(1.0f, expf(-x)));
  float e = expf(x);
  return __fdiv_rn(e, __fadd_rn(1.0f, e));
}

__device__ __forceinline__ float iou_ref(float4 a, float4 b) {
  float yy1 = fmaxf(a.x, b.x);
  float xx1 = fmaxf(a.y, b.y);
  float yy2 = fminf(a.z, b.z);
  float xx2 = fminf(a.w, b.w);
  float ih = fmaxf(__fsub_rn(yy2, yy1), 0.0f);
  float iw = fmaxf(__fsub_rn(xx2, xx1), 0.0f);
  float inter = __fmul_rn(ih, iw);
  float a1 = __fmul_rn(__fsub_rn(a.z, a.x), __fsub_rn(a.w, a.y));
  float a2 = __fmul_rn(__fsub_rn(b.z, b.x), __fsub_rn(b.w, b.y));
  float den = __fadd_rn(__fsub_rn(__fadd_rn(a1, a2), inter), 1e-8f);
  return __fdiv_rn(inter, den);
}

// ---------------------------- anchors (+ counter zeroing) ----------------------

__global__ __launch_bounds__(256) void k_anchors(float4* __restrict__ anchors,
                                                 unsigned int* __restrict__ gcnt,
                                                 unsigned int* __restrict__ oflow) {
  int n = blockIdx.x * 256 + threadIdx.x;
  if (n < NBC) { gcnt[n] = 0u; oflow[n] = 0u; }
  if (n >= NANCH) return;
  int l, off;
  if (n < 36864)      { l = 0; off = 0; }
  else if (n < 46080) { l = 1; off = 36864; }
  else if (n < 48384) { l = 2; off = 46080; }
  else if (n < 48960) { l = 3; off = 48384; }
  else                { l = 4; off = 48960; }
  int stride = 8 << l;
  int feat = 64 >> l;
  int r = n - off;
  int cell = r / 9, a = r - cell * 9;
  int iy = cell / feat, ix = cell - iy * feat;
  int isc = a / 3, ir = a - isc * 3;
  // numpy computes half-sizes in float64, then casts to float32
  double base = exp2((double)isc / 3.0) * (double)stride * 4.0;
  double rt = (ir == 0) ? 1.0 : (ir == 1 ? 0.5 : 2.0);
  double sq = sqrt(rt);
  float hh = (float)(base / sq / 2.0);
  float hw = (float)(base * sq / 2.0);
  float cy = __fmul_rn(__fadd_rn((float)iy, 0.5f), (float)stride);
  float cx = __fmul_rn(__fadd_rn((float)ix, 0.5f), (float)stride);
  anchors[n] = make_float4(__fsub_rn(cy, hh), __fsub_rn(cx, hw),
                           __fadd_rn(cy, hh), __fadd_rn(cx, hw));
}

// ---------------------------- decode -------------------------------------------

__global__ __launch_bounds__(256) void k_decode(const float4* __restrict__ deltas,
                                                const float4* __restrict__ anchors,
                                                float4* __restrict__ boxes) {
  int i = blockIdx.x * 256 + threadIdx.x;
  if (i >= NB * NANCH) return;
  int n = i % NANCH;
  float4 a = anchors[n];
  float4 d = deltas[i];
  float ah = __fsub_rn(a.z, a.x);
  float aw = __fsub_rn(a.w, a.y);
  float acy = __fmul_rn(__fadd_rn(a.x, a.z), 0.5f);
  float acx = __fmul_rn(__fadd_rn(a.y, a.w), 0.5f);
  float cy = __fadd_rn(__fmul_rn(d.x, ah), acy);
  float cx = __fadd_rn(__fmul_rn(d.y, aw), acx);
  float h = __fmul_rn(expf(d.z), ah);
  float w = __fmul_rn(expf(d.w), aw);
  float y1 = __fsub_rn(cy, __fmul_rn(h, 0.5f));
  float x1 = __fsub_rn(cx, __fmul_rn(w, 0.5f));
  float y2 = __fadd_rn(cy, __fmul_rn(h, 0.5f));
  float x2 = __fadd_rn(cx, __fmul_rn(w, 0.5f));
  const float inv = 0.001953125f;  // 1/512, exact
  y1 = fminf(fmaxf(__fmul_rn(y1, inv), 0.0f), 1.0f);
  x1 = fminf(fmaxf(__fmul_rn(x1, inv), 0.0f), 1.0f);
  y2 = fminf(fmaxf(__fmul_rn(y2, inv), 0.0f), 1.0f);
  x2 = fminf(fmaxf(__fmul_rn(x2, inv), 0.0f), 1.0f);
  boxes[i] = make_float4(y1, x1, y2, x2);
}

// ------------- candidate scan: LDS-aggregated, 1 reservation atomic ------------
// (verbatim R7/R9-passing kernel)

__global__ __launch_bounds__(256) void k_scan(const float4* __restrict__ logits4,
                                              unsigned long long* __restrict__ gcand,
                                              unsigned int* __restrict__ gcnt,
                                              unsigned int* __restrict__ oflow) {
  int b = blockIdx.y;
  int ch = blockIdx.x;
  int n0 = ch * CHUNK;
  int rows = min(CHUNK, NANCH - n0);
  const float4* base = logits4 + ((size_t)b * NANCH + n0) * 90 / 4;
  int tot4 = rows * 90 / 4;
  int tid = threadIdx.x;

  __shared__ unsigned long long lc[NC * LCAP];  // 23 KB
  __shared__ unsigned int lcnt[NC];
  for (int c = tid; c < NC; c += 256) lcnt[c] = 0u;
  __syncthreads();

  for (int e4 = tid; e4 < tot4; e4 += 1024) {
    float4 v[4];
#pragma unroll
    for (int k = 0; k < 4; k++) {
      int idx = e4 + k * 256;
      if (idx < tot4) v[k] = base[idx];
    }
#pragma unroll
    for (int k = 0; k < 4; k++) {
      int idx = e4 + k * 256;
      if (idx >= tot4) break;
      float xs[4] = {v[k].x, v[k].y, v[k].z, v[k].w};
#pragma unroll
      for (int j = 0; j < 4; j++) {
        float x = xs[j];
        if (x >= PRECHK) {  // skips sigmoid for ~98% of elements
          float s = sigmoid_ref(x);
          if (s >= EDGE) {
            int e = idx * 4 + j;
            int r = e / 90, c = e - r * 90;
            unsigned int pos = atomicAdd(&lcnt[c], 1u);  // LDS atomic (on-CU)
            if (pos < LCAP) {
              int n = n0 + r;
              lc[c * LCAP + pos] =
                  ((unsigned long long)__float_as_uint(s) << 32) |
                  (unsigned int)(65535 - n);  // u64 desc == score desc, n asc
            }
          }
        }
      }
    }
  }
  __syncthreads();

  // reserve + flush: one global atomic per (class,chunk) with candidates
  if (tid < NC) {
    unsigned int cnt = lcnt[tid];
    int bc = b * NC + tid;
    if (cnt > LCAP) {  // ~1e-16 probability: flag bc for exact fallback
      atomicOr(&oflow[bc], 1u);
      cnt = LCAP;
    }
    if (cnt > 0) {
      unsigned int pos0 = atomicAdd(&gcnt[bc], cnt);
      for (unsigned int k = 0; k < cnt; k++) {
        unsigned int p = pos0 + k;
        if (p < T1CAP) gcand[(size_t)bc * T1CAP + p] = lc[tid * LCAP + k];
      }
    }
  }
}

// -------------------- tier1: sort <=512 candidates + greedy NMS ----------------
// Single-wave. Sort verbatim from R9 (passing). NMS: boxes in 8 float4
// registers per lane (slot t = tid + 64q); suppress sweep = pure VALU;
// next-alive via 8x __ballot + wave-uniform scalar __ffsll; selected box
// broadcast = one uniform LDS read. Exact reference order preserved.

__global__ __launch_bounds__(64) void k_nms_t1(
    const unsigned long long* __restrict__ gcand,
    const unsigned int* __restrict__ gcnt, const unsigned int* __restrict__ oflow,
    const float4* __restrict__ boxes, float* __restrict__ sel_s,
    float4* __restrict__ sel_b, int* __restrict__ flags) {
  int bc = blockIdx.x;
  int b = bc / NC;
  int tid = threadIdx.x;

  __shared__ unsigned long long cand[T1CAP];   // 4 KB
  __shared__ float4 cbox[T1CAP];               // 8 KB
  __shared__ float4 s_selbox[POSTN];
  __shared__ float s_sels[POSTN];

  unsigned int cnt = gcnt[bc];
  bool overflow = (cnt > (unsigned)T1CAP) || (oflow[bc] != 0u);
  int M = (int)min(cnt, (unsigned)T1CAP);
  for (int e = tid; e < T1CAP; e += 64)
    cand[e] = (e < M) ? gcand[(size_t)bc * T1CAP + e] : 0ull;
  __syncthreads();

  // bitonic sort descending (key = score desc, tie idx asc via 65535-n packing)
  // adaptive size: zero-padding beyond M means sorting the first SN suffices.
  int SN = (M <= 128) ? 128 : (M <= 256) ? 256 : 512;
  int np = SN >> 1;  // pairs per stage (64..256)
  for (int k = 2; k <= SN; k <<= 1) {
    for (int j = k >> 1; j > 0; j >>= 1) {
      unsigned long long a[4], bb[4];
      int ii[4];
#pragma unroll
      for (int q = 0; q < 4; q++) {
        int t = tid + (q << 6);
        if (t < np) {
          int i = ((t & ~(j - 1)) << 1) | (t & (j - 1));
          ii[q] = i;
          a[q] = cand[i];
          bb[q] = cand[i | j];
        } else {
          ii[q] = -1;
        }
      }
#pragma unroll
      for (int q = 0; q < 4; q++) {
        if (ii[q] >= 0) {
          bool up = ((ii[q] & k) == 0);
          if (up ? (a[q] < bb[q]) : (a[q] > bb[q])) {
            cand[ii[q]] = bb[q];
            cand[ii[q] | j] = a[q];
          }
        }
      }
      __syncthreads();
    }
  }

  // gather boxes into REGISTERS (8 owned slots t = tid + 64q) + LDS broadcast
  // copy; per-lane alive bitmask in amask.
  float4 bx0, bx1, bx2, bx3, bx4, bx5, bx6, bx7;
  bx0 = bx1 = bx2 = bx3 = bx4 = bx5 = bx6 = bx7 = make_float4(0, 0, 0, 0);
  unsigned int amask = 0u;
#define GATHER(Q, REG)                                        \
  {                                                           \
    int t = tid + (Q << 6);                                   \
    if (t < M) {                                              \
      int n = 65535 - (int)(cand[t] & 0xFFFFull);             \
      REG = boxes[(size_t)b * NANCH + n];                     \
      cbox[t] = REG;                                          \
      amask |= (1u << Q);                                     \
    }                                                         \
  }
  GATHER(0, bx0) GATHER(1, bx1) GATHER(2, bx2) GATHER(3, bx3)
  GATHER(4, bx4) GATHER(5, bx5) GATHER(6, bx6) GATHER(7, bx7)
#undef GATHER
  __syncthreads();

  // serial greedy NMS, wave-synchronous (exact reference order)
  int nsel = 0;
  int i = 0;
  while (i < M && nsel < POSTN) {
    float4 bi = cbox[i];  // uniform address -> LDS broadcast, same on all lanes
    float sc = __uint_as_float((unsigned int)(cand[i] >> 32));
    if (!(iou_ref(bi, bi) > 0.5f)) {
      // degenerate zero-area box: never self-suppresses -> reference re-selects
      // it for every remaining step ("sticky" fill)
      if (tid == 0) {
        for (int p = nsel; p < POSTN; p++) { s_selbox[p] = bi; s_sels[p] = sc; }
      }
      nsel = POSTN;
      break;
    }
    if (tid == 0) { s_selbox[nsel] = bi; s_sels[nsel] = sc; }
    nsel++;
    // suppress owned alive slots with t > i (registers only)
#define SWEEP(Q, REG)                                                   \
  {                                                                     \
    int t = tid + (Q << 6);                                             \
    if (((amask >> Q) & 1u) && t > i) {                                 \
      if (iou_ref(REG, bi) > 0.5f) amask &= ~(1u << Q);                 \
    }                                                                   \
  }
    SWEEP(0, bx0) SWEEP(1, bx1) SWEEP(2, bx2) SWEEP(3, bx3)
    SWEEP(4, bx4) SWEEP(5, bx5) SWEEP(6, bx6) SWEEP(7, bx7)
#undef SWEEP
    // next alive index > i: per-q wave ballots + uniform scalar find.
    // slot t = q*64 + lane, so (q, lane) lexicographic == t ascending.
    int qi = i >> 6, ti = i & 63;
    int nxt = M;
#pragma unroll
    for (int q = 0; q < 8; q++) {
      unsigned long long bal = __ballot((int)((amask >> q) & 1u));
      unsigned long long gt =
          (q > qi) ? ~0ull
                   : ((q < qi) ? 0ull
                               : ((ti >= 63) ? 0ull : ((~0ull) << (ti + 1))));
      unsigned long long m = bal & gt;
      if (nxt == M && m != 0ull) nxt = (q << 6) + (__ffsll((unsigned long long)m) - 1);
    }
    i = nxt;
  }
  __syncthreads();

  // valid only if 100 selections completed from a complete (non-overflowed) list
  bool bad = overflow || (nsel < POSTN);
  if (tid == 0) flags[bc] = bad ? 1 : 0;
  if (bad) return;
  for (int p = tid; p < POSTN; p += 64) {
    float s0 = s_sels[p];
    bool valid = (s0 > 0.2f);  // SCORE_THR gate (always true here: s0>=EDGE)
    sel_s[bc * POSTN + p] = valid ? s0 : 0.0f;
    sel_b[bc * POSTN + p] = valid ? s_selbox[p] : make_float4(0, 0, 0, 0);
  }
}

// -------- flag-all helper (only if workspace too small for scan buffers) -------

__global__ __launch_bounds__(256) void k_flagall(int* __restrict__ flags) {
  int i = blockIdx.x * 256 + threadIdx.x;
  if (i < NBC) flags[i] = 1;
}

// -------- exact fallback: histogram rank-5000 + sort + NMS (rare/never) --------

template <int CAP, int RANK>
__global__ __launch_bounds__(256) void k_nms_fb(const float* __restrict__ logits,
                                                const float4* __restrict__ boxes,
                                                float* __restrict__ sel_s,
                                                float4* __restrict__ sel_b,
                                                const int* __restrict__ flags) {
  int bc = blockIdx.x;
  if (flags[bc] == 0) return;
  int b = bc / NC;
  int c = bc - b * NC;
  int tid = threadIdx.x;

  __shared__ unsigned int s_key[CAP];
  __shared__ unsigned short s_idx[CAP];
  __shared__ __align__(16) unsigned char s_pool[8192];
  __shared__ unsigned int s_bsum[256];
  __shared__ unsigned char s_alive[512];
  __shared__ float4 s_selbox[POSTN];
  __shared__ float s_sels[POSTN];
  __shared__ int s_cnt, s_nsel, s_cutbin;

  const float* lrow = logits + (size_t)b * NANCH * 90 + c;

  unsigned int* hist = (unsigned int*)s_pool;
  for (int e = tid; e < 2048; e += 256) hist[e] = 0u;
  if (tid == 0) { s_cnt = 0; s_nsel = 0; s_cutbin = 0; }
  __syncthreads();

  for (int n = tid; n < NANCH; n += 256) {
    float s = sigmoid_ref(lrow[(size_t)n * 90]);
    int bin = (int)(s * 2048.0f);
    if (bin > 2047) bin = 2047;
    atomicAdd(&hist[bin], 1u);
  }
  __syncthreads();
  unsigned int loc = 0;
#pragma unroll
  for (int k = 0; k < 8; k++) loc += hist[tid * 8 + k];
  s_bsum[tid] = loc;
  __syncthreads();
  if (tid == 0) {
    unsigned int cum = 0;
    int bin = 0;
    bool fnd = false;
    for (int t = 255; t >= 0 && !fnd; t--) {
      if (cum + s_bsum[t] >= (unsigned)RANK) {
        for (int kk = 7; kk >= 0; kk--) {
          unsigned int h = hist[t * 8 + kk];
          if (cum + h >= (unsigned)RANK) { bin = t * 8 + kk; fnd = true; break; }
          cum += h;
        }
      } else {
        cum += s_bsum[t];
      }
    }
    s_cutbin = bin;
  }
  __syncthreads();
  float edge = __fmul_rn((float)s_cutbin, (1.0f / 2048.0f));  // exact

  for (int n = tid; n < NANCH; n += 256) {
    float s = sigmoid_ref(lrow[(size_t)n * 90]);
    if (s >= edge) {
      int pos = atomicAdd(&s_cnt, 1);
      if (pos < CAP) {
        s_key[pos] = __float_as_uint(s);
        s_idx[pos] = (unsigned short)n;
      }
    }
  }
  __syncthreads();
  int M = s_cnt;
  if (M > CAP) M = CAP;
  for (int e = M + tid; e < CAP; e += 256) { s_key[e] = 0u; s_idx[e] = 0xFFFFu; }
  __syncthreads();

  for (int k = 2; k <= CAP; k <<= 1) {
    for (int j = k >> 1; j > 0; j >>= 1) {
      for (int t = tid; t < CAP / 2; t += 256) {
        int i = ((t & ~(j - 1)) << 1) | (t & (j - 1));
        int p = i | j;
        unsigned int ka = s_key[i], kb = s_key[p];
        unsigned short ia = s_idx[i], ib = s_idx[p];
        bool up = ((i & k) == 0);
        bool g = (ka < kb) || (ka == kb && ia > ib);
        bool l = (kb < ka) || (ka == kb && ib > ia);
        if (up ? g : l) {
          s_key[i] = kb; s_key[p] = ka;
          s_idx[i] = ib; s_idx[p] = ia;
        }
      }
      __syncthreads();
    }
  }

  float4* cbox = (float4*)s_pool;
  int L = (M < 5000) ? M : 5000;  // PRE_NMS truncation (stable)
  for (int base = 0; base < L; base += 512) {
    int cn = min(512, L - base);
    int ns0 = s_nsel;
    if (ns0 >= POSTN) break;
    for (int t = tid; t < cn; t += 256) {
      int n = s_idx[base + t];
      float4 bx = boxes[(size_t)b * NANCH + n];
      bool al = true;
      for (int s = 0; s < ns0; s++) {
        if (iou_ref(bx, s_selbox[s]) > 0.5f) { al = false; break; }
      }
      cbox[t] = bx;
      s_alive[t] = al ? 1 : 0;
    }
    __syncthreads();
    for (int i = 0; i < cn; i++) {
      if (s_nsel >= POSTN) break;
      if (!s_alive[i]) continue;
      float4 bi = cbox[i];
      float sc = __uint_as_float(s_key[base + i]);
      if (!(iou_ref(bi, bi) > 0.5f)) {
        if (tid == 0) {
          for (int p = s_nsel; p < POSTN; p++) { s_selbox[p] = bi; s_sels[p] = sc; }
          s_nsel = POSTN;
        }
        __syncthreads();
        break;
      }
      for (int t = tid; t < cn; t += 256) {
        if (t > i && s_alive[t] && iou_ref(cbox[t], bi) > 0.5f) s_alive[t] = 0;
      }
      if (tid == 0) {
        s_selbox[s_nsel] = bi;
        s_sels[s_nsel] = sc;
        s_nsel = s_nsel + 1;
      }
      __syncthreads();
    }
    __syncthreads();
    if (s_nsel >= POSTN) break;
  }
  __syncthreads();
  int ns = s_nsel;
  for (int p = tid; p < POSTN; p += 256) {
    float sc = 0.0f;
    float4 bx = make_float4(0.0f, 0.0f, 0.0f, 0.0f);
    if (p < ns) {
      float s0 = s_sels[p];
      if (s0 > 0.2f) { sc = s0; bx = s_selbox[p]; }
    }
    sel_s[bc * POSTN + p] = sc;
    sel_b[bc * POSTN + p] = bx;
  }
}

// ---------------- per-batch top-100: frontier merge, single-wave ----------------
// (verbatim R9-passing kernel)

__global__ __launch_bounds__(64) void k_final(const float* __restrict__ sel_s,
                                              const float4* __restrict__ sel_b,
                                              float* __restrict__ out) {
  int b = blockIdx.x;
  int tid = threadIdx.x;
  __shared__ float key[9000];
  __shared__ unsigned int win_k[POSTN];
  __shared__ int win_e[POSTN];
  for (int e = tid; e < 9000; e += 64) key[e] = sel_s[(size_t)b * 9000 + e];
  int p0 = 0, p1 = 0;       // frontier ptrs for classes tid and tid+64
  int c1 = tid + 64;        // valid iff c1 < NC (lanes 0..25)
  __syncthreads();
  for (int p = 0; p < POSTN; p++) {
    unsigned long long v = 0ull;
    if (p0 < POSTN) {
      int e = tid * POSTN + p0;
      v = ((unsigned long long)__float_as_uint(key[e]) << 32) |
          (unsigned int)(16383 - e);  // max score, then min flat idx (stable)
    }
    if (c1 < NC && p1 < POSTN) {
      int e = c1 * POSTN + p1;
      unsigned long long v2 = ((unsigned long long)__float_as_uint(key[e]) << 32) |
                              (unsigned int)(16383 - e);
      if (v2 > v) v = v2;
    }
#pragma unroll
    for (int d = 1; d < 64; d <<= 1) {
      unsigned long long o = __shfl_xor(v, d, 64);
      if (o > v) v = o;
    }
    int e = 16383 - (int)(v & 0x3FFFull);
    if (tid == 0) { win_k[p] = (unsigned int)(v >> 32); win_e[p] = e; }
    int cls = e / POSTN;
    int pp = e - cls * POSTN;
    if (cls == tid) p0 = pp + 1;
    else if (cls == c1) p1 = pp + 1;
  }
  __syncthreads();
  for (int p = tid; p < POSTN; p += 64) {
    unsigned int k = win_k[p];
    int e = win_e[p];
    float4 bx = sel_b[(size_t)b * 9000 + e];
    ((float4*)out)[b * POSTN + p] = bx;              // out_b [8,100,4]
    out[3200 + b * POSTN + p] = __uint_as_float(k);  // out_s [8,100]
    out[4000 + b * POSTN + p] = (float)(e / POSTN);  // out_c [8,100]
  }
  int vcnt = 0;
  for (int p = tid; p < POSTN; p += 64) vcnt += (win_k[p] != 0u) ? 1 : 0;
#pragma unroll
  for (int d = 1; d < 64; d <<= 1) vcnt += __shfl_xor(vcnt, d, 64);
  if (tid == 0) out[4800 + b] = (float)vcnt;  // valid [8]
}

// ------------------------------- launcher --------------------------------------

extern "C" void kernel_launch(void* const* d_in, const int* in_sizes, int n_in,
                              void* d_out, int out_size, void* d_ws, size_t ws_size,
                              hipStream_t stream) {
  const float* deltas = (const float*)d_in[0];  // [8,49104,4]
  const float* logits = (const float*)d_in[1];  // [8,49104,90]
  float* out = (float*)d_out;
  char* ws = (char*)d_ws;

  size_t off = 0;
  auto take = [&](size_t bytes) -> char* {
    char* p = ws + off;
    off += (bytes + 255) & ~(size_t)255;
    return p;
  };
  // small/required buffers first so the degraded path fits in ~8.6 MB
  float4* anchors = (float4*)take((size_t)NANCH * 16);
  float4* boxes = (float4*)take((size_t)NB * NANCH * 16);
  float* sel_s = (float*)take((size_t)NBC * POSTN * 4);
  float4* sel_b = (float4*)take((size_t)NBC * POSTN * 16);
  int* flags = (int*)take((size_t)NBC * 4);
  unsigned int* gcnt = (unsigned int*)take((size_t)NBC * 4);
  unsigned int* oflow = (unsigned int*)take((size_t)NBC * 4);
  unsigned long long* gcand =
      (unsigned long long*)take((size_t)NBC * T1CAP * 8);
  bool fits = (off <= ws_size);  // total ~11.5 MB

  k_anchors<<<dim3((NANCH + 255) / 256), dim3(256), 0, stream>>>(anchors, gcnt,
                                                                 oflow);
  k_decode<<<dim3((NB * NANCH + 255) / 256), dim3(256), 0, stream>>>(
      (const float4*)deltas, anchors, boxes);
  if (fits) {
    k_scan<<<dim3(NCH, NB), dim3(256), 0, stream>>>((const float4*)logits,
                                                    gcand, gcnt, oflow);
    k_nms_t1<<<dim3(NBC), dim3(64), 0, stream>>>(gcand, gcnt, oflow, boxes,
                                                 sel_s, sel_b, flags);
  } else {
    k_flagall<<<dim3((NBC + 255) / 256), dim3(256), 0, stream>>>(flags);
  }
  k_nms_fb<8192, 5000><<<dim3(NBC), dim3(256), 0, stream>>>(logits, boxes,
                                                            sel_s, sel_b, flags);
  k_final<<<dim3(NB), dim3(64), 0, stream>>>(sel_s, sel_b, out);
}

// Round 5
// 358.625 us; speedup vs baseline: 1.1508x; 1.1348x over previous
//
#include <hip/hip_runtime.h>
#include <math.h>

// EfficientDet postprocess for MI355X — round 11.
// R10 post-mortem: t1 141us, VALUBusy 14%, occupancy 7% — the serial greedy
// loop is a ~100-step dependent latency chain on a solo wave. Evidence across
// R6/R7/R9/R10: intra-block wave parallelism is what helps. This round splits
// the algorithm:
//   (1) suppression-matrix build (exact pairwise iou>thr bits, j>=i, self-bit
//       encodes degenerate-sticky) across 256 threads / 4 waves via __ballot
//       (row word == one wave ballot) — throughput-bound, ~4us.
//   (2) greedy scan becomes 100 steps of {ffs-find-first-alive,
//       alive &= ~rows[i]} — one 8-lane LDS read per step, ~220cy/step.
// Greedy equivalence is exact: when i is selected all alive j satisfy j>i
// (sorted order + first-alive), so j>=i bits suffice; bit i = self-iou>thr
// (zero-area box never self-clears -> sticky refill, matching reference).
// Sort restored to R7-proven 256-thread mapping + R9/R10-proven adaptive SN.
// All other kernels verbatim from the passing R10 build.

#define NANCH 49104
#define NB 8
#define NC 90
#define NBC 720
#define POSTN 100
#define T1CAP 512
#define WMAX 8          // T1CAP/64 row words
#define CHUNK 512
#define NCH 96          // ceil(49104/512)
#define LCAP 32         // per-(class,chunk) LDS list cap
#define EDGE 0.93f      // P(sigmoid(N(0,1)) >= 0.93) ~ 0.484% -> ~238 +/- 15 per (b,c)
#define PRECHK 2.0f     // sigmoid(2.0)=0.8808 < EDGE: safe cheap pre-filter

// ---------- exact-float helpers (mirror numpy f32 semantics, no FMA) ----------

__device__ __forceinline__ float sigmoid_ref(float x) {
  if (x >= 0.0f) return __fdiv_rn(1.0f, __fadd_rn(1.0f, expf(-x)));
  float e = expf(x);
  return __fdiv_rn(e, __fadd_rn(1.0f, e));
}

__device__ __forceinline__ float iou_ref(float4 a, float4 b) {
  float yy1 = fmaxf(a.x, b.x);
  float xx1 = fmaxf(a.y, b.y);
  float yy2 = fminf(a.z, b.z);
  float xx2 = fminf(a.w, b.w);
  float ih = fmaxf(__fsub_rn(yy2, yy1), 0.0f);
  float iw = fmaxf(__fsub_rn(xx2, xx1), 0.0f);
  float inter = __fmul_rn(ih, iw);
  float a1 = __fmul_rn(__fsub_rn(a.z, a.x), __fsub_rn(a.w, a.y));
  float a2 = __fmul_rn(__fsub_rn(b.z, b.x), __fsub_rn(b.w, b.y));
  float den = __fadd_rn(__fsub_rn(__fadd_rn(a1, a2), inter), 1e-8f);
  return __fdiv_rn(inter, den);
}

// ---------------------------- anchors (+ counter zeroing) ----------------------

__global__ __launch_bounds__(256) void k_anchors(float4* __restrict__ anchors,
                                                 unsigned int* __restrict__ gcnt,
                                                 unsigned int* __restrict__ oflow) {
  int n = blockIdx.x * 256 + threadIdx.x;
  if (n < NBC) { gcnt[n] = 0u; oflow[n] = 0u; }
  if (n >= NANCH) return;
  int l, off;
  if (n < 36864)      { l = 0; off = 0; }
  else if (n < 46080) { l = 1; off = 36864; }
  else if (n < 48384) { l = 2; off = 46080; }
  else if (n < 48960) { l = 3; off = 48384; }
  else                { l = 4; off = 48960; }
  int stride = 8 << l;
  int feat = 64 >> l;
  int r = n - off;
  int cell = r / 9, a = r - cell * 9;
  int iy = cell / feat, ix = cell - iy * feat;
  int isc = a / 3, ir = a - isc * 3;
  // numpy computes half-sizes in float64, then casts to float32
  double base = exp2((double)isc / 3.0) * (double)stride * 4.0;
  double rt = (ir == 0) ? 1.0 : (ir == 1 ? 0.5 : 2.0);
  double sq = sqrt(rt);
  float hh = (float)(base / sq / 2.0);
  float hw = (float)(base * sq / 2.0);
  float cy = __fmul_rn(__fadd_rn((float)iy, 0.5f), (float)stride);
  float cx = __fmul_rn(__fadd_rn((float)ix, 0.5f), (float)stride);
  anchors[n] = make_float4(__fsub_rn(cy, hh), __fsub_rn(cx, hw),
                           __fadd_rn(cy, hh), __fadd_rn(cx, hw));
}

// ---------------------------- decode -------------------------------------------

__global__ __launch_bounds__(256) void k_decode(const float4* __restrict__ deltas,
                                                const float4* __restrict__ anchors,
                                                float4* __restrict__ boxes) {
  int i = blockIdx.x * 256 + threadIdx.x;
  if (i >= NB * NANCH) return;
  int n = i % NANCH;
  float4 a = anchors[n];
  float4 d = deltas[i];
  float ah = __fsub_rn(a.z, a.x);
  float aw = __fsub_rn(a.w, a.y);
  float acy = __fmul_rn(__fadd_rn(a.x, a.z), 0.5f);
  float acx = __fmul_rn(__fadd_rn(a.y, a.w), 0.5f);
  float cy = __fadd_rn(__fmul_rn(d.x, ah), acy);
  float cx = __fadd_rn(__fmul_rn(d.y, aw), acx);
  float h = __fmul_rn(expf(d.z), ah);
  float w = __fmul_rn(expf(d.w), aw);
  float y1 = __fsub_rn(cy, __fmul_rn(h, 0.5f));
  float x1 = __fsub_rn(cx, __fmul_rn(w, 0.5f));
  float y2 = __fadd_rn(cy, __fmul_rn(h, 0.5f));
  float x2 = __fadd_rn(cx, __fmul_rn(w, 0.5f));
  const float inv = 0.001953125f;  // 1/512, exact
  y1 = fminf(fmaxf(__fmul_rn(y1, inv), 0.0f), 1.0f);
  x1 = fminf(fmaxf(__fmul_rn(x1, inv), 0.0f), 1.0f);
  y2 = fminf(fmaxf(__fmul_rn(y2, inv), 0.0f), 1.0f);
  x2 = fminf(fmaxf(__fmul_rn(x2, inv), 0.0f), 1.0f);
  boxes[i] = make_float4(y1, x1, y2, x2);
}

// ------------- candidate scan: LDS-aggregated, 1 reservation atomic ------------
// (verbatim R7/R9/R10-passing kernel)

__global__ __launch_bounds__(256) void k_scan(const float4* __restrict__ logits4,
                                              unsigned long long* __restrict__ gcand,
                                              unsigned int* __restrict__ gcnt,
                                              unsigned int* __restrict__ oflow) {
  int b = blockIdx.y;
  int ch = blockIdx.x;
  int n0 = ch * CHUNK;
  int rows = min(CHUNK, NANCH - n0);
  const float4* base = logits4 + ((size_t)b * NANCH + n0) * 90 / 4;
  int tot4 = rows * 90 / 4;
  int tid = threadIdx.x;

  __shared__ unsigned long long lc[NC * LCAP];  // 23 KB
  __shared__ unsigned int lcnt[NC];
  for (int c = tid; c < NC; c += 256) lcnt[c] = 0u;
  __syncthreads();

  for (int e4 = tid; e4 < tot4; e4 += 1024) {
    float4 v[4];
#pragma unroll
    for (int k = 0; k < 4; k++) {
      int idx = e4 + k * 256;
      if (idx < tot4) v[k] = base[idx];
    }
#pragma unroll
    for (int k = 0; k < 4; k++) {
      int idx = e4 + k * 256;
      if (idx >= tot4) break;
      float xs[4] = {v[k].x, v[k].y, v[k].z, v[k].w};
#pragma unroll
      for (int j = 0; j < 4; j++) {
        float x = xs[j];
        if (x >= PRECHK) {  // skips sigmoid for ~98% of elements
          float s = sigmoid_ref(x);
          if (s >= EDGE) {
            int e = idx * 4 + j;
            int r = e / 90, c = e - r * 90;
            unsigned int pos = atomicAdd(&lcnt[c], 1u);  // LDS atomic (on-CU)
            if (pos < LCAP) {
              int n = n0 + r;
              lc[c * LCAP + pos] =
                  ((unsigned long long)__float_as_uint(s) << 32) |
                  (unsigned int)(65535 - n);  // u64 desc == score desc, n asc
            }
          }
        }
      }
    }
  }
  __syncthreads();

  // reserve + flush: one global atomic per (class,chunk) with candidates
  if (tid < NC) {
    unsigned int cnt = lcnt[tid];
    int bc = b * NC + tid;
    if (cnt > LCAP) {  // ~1e-16 probability: flag bc for exact fallback
      atomicOr(&oflow[bc], 1u);
      cnt = LCAP;
    }
    if (cnt > 0) {
      unsigned int pos0 = atomicAdd(&gcnt[bc], cnt);
      for (unsigned int k = 0; k < cnt; k++) {
        unsigned int p = pos0 + k;
        if (p < T1CAP) gcand[(size_t)bc * T1CAP + p] = lc[tid * LCAP + k];
      }
    }
  }
}

// ------------- tier1: sort + suppression matrix + bitmask greedy scan ----------

__global__ __launch_bounds__(256) void k_nms_t1(
    const unsigned long long* __restrict__ gcand,
    const unsigned int* __restrict__ gcnt, const unsigned int* __restrict__ oflow,
    const float4* __restrict__ boxes, float* __restrict__ sel_s,
    float4* __restrict__ sel_b, int* __restrict__ flags) {
  int bc = blockIdx.x;
  int b = bc / NC;
  int tid = threadIdx.x;
  int lane = tid & 63;
  int wv = tid >> 6;

  __shared__ unsigned long long cand[T1CAP];          // 4 KB
  __shared__ float4 cbox[T1CAP];                      // 8 KB
  __shared__ unsigned long long rowm[T1CAP][WMAX];    // 32 KB
  __shared__ int s_seli[POSTN];
  __shared__ int s_nsel;

  unsigned int cnt = gcnt[bc];
  bool overflow = (cnt > (unsigned)T1CAP) || (oflow[bc] != 0u);
  int M = (int)min(cnt, (unsigned)T1CAP);
  for (int e = tid; e < T1CAP; e += 256)
    cand[e] = (e < M) ? gcand[(size_t)bc * T1CAP + e] : 0ull;
  if (tid == 0) s_nsel = 0;
  __syncthreads();

  // bitonic sort descending (key = score desc, tie idx asc via 65535-n packing)
  // R7-proven 256-thread mapping; adaptive SN (zero-padding beyond M).
  int SN = (M <= 128) ? 128 : (M <= 256) ? 256 : 512;
  int np = SN >> 1;
  for (int k = 2; k <= SN; k <<= 1) {
    for (int j = k >> 1; j > 0; j >>= 1) {
      int t = tid;
      if (t < np) {
        int i = ((t & ~(j - 1)) << 1) | (t & (j - 1));
        int p = i | j;
        unsigned long long a = cand[i], bb = cand[p];
        bool up = ((i & k) == 0);
        if (up ? (a < bb) : (a > bb)) { cand[i] = bb; cand[p] = a; }
      }
      __syncthreads();
    }
  }

  // gather boxes (sorted order) -> LDS; zero-fill tail so j-regs need no guard
  for (int e = tid; e < T1CAP; e += 256) {
    if (e < M) {
      int n = 65535 - (int)(cand[e] & 0xFFFFull);
      cbox[e] = boxes[(size_t)b * NANCH + n];
    } else {
      cbox[e] = make_float4(0.0f, 0.0f, 0.0f, 0.0f);
    }
  }
  __syncthreads();

  // per-lane j-register copies (identical in every wave): jb[w] = cbox[w*64+lane]
  float4 jb[WMAX];
#pragma unroll
  for (int w = 0; w < WMAX; w++) jb[w] = cbox[(w << 6) + lane];

  int W = (M + 63) >> 6;  // active row words

  // build suppression rows: wave wv handles rows i = wv, wv+4, ...
  // row i word w: bit(lane) = j>=i && j<M && iou(box_j, box_i) > 0.5, j=w*64+lane.
  // bit i (self) = iou(bi,bi)>0.5: normal box -> clears itself after selection;
  // zero-area box -> stays alive -> sticky refill (reference semantics).
  for (int i = wv; i < M; i += 4) {
    float4 bi = cbox[i];  // wave-uniform -> LDS broadcast
    int w0 = i >> 6;
    unsigned long long myw = 0ull;
#pragma unroll
    for (int w = 0; w < WMAX; w++) {
      unsigned long long rw = 0ull;
      if (w >= w0 && w < W) {
        int j = (w << 6) + lane;
        bool bit = (j >= i) && (j < M) && (iou_ref(jb[w], bi) > 0.5f);
        rw = __ballot((int)bit);
      }
      if (lane == w) myw = rw;
    }
    if (lane < WMAX) rowm[i][lane] = myw;
  }
  __syncthreads();

  // greedy scan (wave 0): 100 steps of find-first-alive + AND-out its row.
  if (wv == 0) {
    unsigned long long av = 0ull;
    if (lane < W) {
      int mw = M >> 6;
      if (lane < mw) av = ~0ull;
      else if (lane == mw) av = (M & 63) ? ((1ull << (M & 63)) - 1ull) : 0ull;
    }
    int nsel = 0;
    for (int p = 0; p < POSTN; p++) {
      int idx = 0x7FFFFFFF;
      if (lane < W && av != 0ull) idx = (lane << 6) + __ffsll(av) - 1;
#pragma unroll
      for (int d = 1; d < 8; d <<= 1) {
        int o = __shfl_xor(idx, d, 64);
        idx = min(idx, o);
      }
      idx = __shfl(idx, 0, 64);  // broadcast true min to whole wave
      if (idx == 0x7FFFFFFF) break;  // starvation -> bad -> fallback
      if (lane == 0) s_seli[p] = idx;
      nsel++;
      unsigned long long rw = 0ull;
      if (lane < W) rw = rowm[idx][lane];
      av &= ~rw;
    }
    if (lane == 0) s_nsel = nsel;
  }
  __syncthreads();

  // valid only if 100 selections completed from a complete (non-overflowed) list
  int ns = s_nsel;
  bool bad = overflow || (ns < POSTN);
  if (tid == 0) flags[bc] = bad ? 1 : 0;
  if (bad) return;
  for (int p = tid; p < POSTN; p += 256) {
    int i = s_seli[p];
    float s0 = __uint_as_float((unsigned int)(cand[i] >> 32));
    float4 bx = cbox[i];
    bool valid = (s0 > 0.2f);  // SCORE_THR gate (always true here: s0>=EDGE)
    sel_s[bc * POSTN + p] = valid ? s0 : 0.0f;
    sel_b[bc * POSTN + p] = valid ? bx : make_float4(0, 0, 0, 0);
  }
}

// -------- flag-all helper (only if workspace too small for scan buffers) -------

__global__ __launch_bounds__(256) void k_flagall(int* __restrict__ flags) {
  int i = blockIdx.x * 256 + threadIdx.x;
  if (i < NBC) flags[i] = 1;
}

// -------- exact fallback: histogram rank-5000 + sort + NMS (rare/never) --------

template <int CAP, int RANK>
__global__ __launch_bounds__(256) void k_nms_fb(const float* __restrict__ logits,
                                                const float4* __restrict__ boxes,
                                                float* __restrict__ sel_s,
                                                float4* __restrict__ sel_b,
                                                const int* __restrict__ flags) {
  int bc = blockIdx.x;
  if (flags[bc] == 0) return;
  int b = bc / NC;
  int c = bc - b * NC;
  int tid = threadIdx.x;

  __shared__ unsigned int s_key[CAP];
  __shared__ unsigned short s_idx[CAP];
  __shared__ __align__(16) unsigned char s_pool[8192];
  __shared__ unsigned int s_bsum[256];
  __shared__ unsigned char s_alive[512];
  __shared__ float4 s_selbox[POSTN];
  __shared__ float s_sels[POSTN];
  __shared__ int s_cnt, s_nsel, s_cutbin;

  const float* lrow = logits + (size_t)b * NANCH * 90 + c;

  unsigned int* hist = (unsigned int*)s_pool;
  for (int e = tid; e < 2048; e += 256) hist[e] = 0u;
  if (tid == 0) { s_cnt = 0; s_nsel = 0; s_cutbin = 0; }
  __syncthreads();

  for (int n = tid; n < NANCH; n += 256) {
    float s = sigmoid_ref(lrow[(size_t)n * 90]);
    int bin = (int)(s * 2048.0f);
    if (bin > 2047) bin = 2047;
    atomicAdd(&hist[bin], 1u);
  }
  __syncthreads();
  unsigned int loc = 0;
#pragma unroll
  for (int k = 0; k < 8; k++) loc += hist[tid * 8 + k];
  s_bsum[tid] = loc;
  __syncthreads();
  if (tid == 0) {
    unsigned int cum = 0;
    int bin = 0;
    bool fnd = false;
    for (int t = 255; t >= 0 && !fnd; t--) {
      if (cum + s_bsum[t] >= (unsigned)RANK) {
        for (int kk = 7; kk >= 0; kk--) {
          unsigned int h = hist[t * 8 + kk];
          if (cum + h >= (unsigned)RANK) { bin = t * 8 + kk; fnd = true; break; }
          cum += h;
        }
      } else {
        cum += s_bsum[t];
      }
    }
    s_cutbin = bin;
  }
  __syncthreads();
  float edge = __fmul_rn((float)s_cutbin, (1.0f / 2048.0f));  // exact

  for (int n = tid; n < NANCH; n += 256) {
    float s = sigmoid_ref(lrow[(size_t)n * 90]);
    if (s >= edge) {
      int pos = atomicAdd(&s_cnt, 1);
      if (pos < CAP) {
        s_key[pos] = __float_as_uint(s);
        s_idx[pos] = (unsigned short)n;
      }
    }
  }
  __syncthreads();
  int M = s_cnt;
  if (M > CAP) M = CAP;
  for (int e = M + tid; e < CAP; e += 256) { s_key[e] = 0u; s_idx[e] = 0xFFFFu; }
  __syncthreads();

  for (int k = 2; k <= CAP; k <<= 1) {
    for (int j = k >> 1; j > 0; j >>= 1) {
      for (int t = tid; t < CAP / 2; t += 256) {
        int i = ((t & ~(j - 1)) << 1) | (t & (j - 1));
        int p = i | j;
        unsigned int ka = s_key[i], kb = s_key[p];
        unsigned short ia = s_idx[i], ib = s_idx[p];
        bool up = ((i & k) == 0);
        bool g = (ka < kb) || (ka == kb && ia > ib);
        bool l = (kb < ka) || (ka == kb && ib > ia);
        if (up ? g : l) {
          s_key[i] = kb; s_key[p] = ka;
          s_idx[i] = ib; s_idx[p] = ia;
        }
      }
      __syncthreads();
    }
  }

  float4* cbox = (float4*)s_pool;
  int L = (M < 5000) ? M : 5000;  // PRE_NMS truncation (stable)
  for (int base = 0; base < L; base += 512) {
    int cn = min(512, L - base);
    int ns0 = s_nsel;
    if (ns0 >= POSTN) break;
    for (int t = tid; t < cn; t += 256) {
      int n = s_idx[base + t];
      float4 bx = boxes[(size_t)b * NANCH + n];
      bool al = true;
      for (int s = 0; s < ns0; s++) {
        if (iou_ref(bx, s_selbox[s]) > 0.5f) { al = false; break; }
      }
      cbox[t] = bx;
      s_alive[t] = al ? 1 : 0;
    }
    __syncthreads();
    for (int i = 0; i < cn; i++) {
      if (s_nsel >= POSTN) break;
      if (!s_alive[i]) continue;
      float4 bi = cbox[i];
      float sc = __uint_as_float(s_key[base + i]);
      if (!(iou_ref(bi, bi) > 0.5f)) {
        if (tid == 0) {
          for (int p = s_nsel; p < POSTN; p++) { s_selbox[p] = bi; s_sels[p] = sc; }
          s_nsel = POSTN;
        }
        __syncthreads();
        break;
      }
      for (int t = tid; t < cn; t += 256) {
        if (t > i && s_alive[t] && iou_ref(cbox[t], bi) > 0.5f) s_alive[t] = 0;
      }
      if (tid == 0) {
        s_selbox[s_nsel] = bi;
        s_sels[s_nsel] = sc;
        s_nsel = s_nsel + 1;
      }
      __syncthreads();
    }
    __syncthreads();
    if (s_nsel >= POSTN) break;
  }
  __syncthreads();
  int ns = s_nsel;
  for (int p = tid; p < POSTN; p += 256) {
    float sc = 0.0f;
    float4 bx = make_float4(0.0f, 0.0f, 0.0f, 0.0f);
    if (p < ns) {
      float s0 = s_sels[p];
      if (s0 > 0.2f) { sc = s0; bx = s_selbox[p]; }
    }
    sel_s[bc * POSTN + p] = sc;
    sel_b[bc * POSTN + p] = bx;
  }
}

// ---------------- per-batch top-100: frontier merge, single-wave ----------------
// (verbatim R9/R10-passing kernel)

__global__ __launch_bounds__(64) void k_final(const float* __restrict__ sel_s,
                                              const float4* __restrict__ sel_b,
                                              float* __restrict__ out) {
  int b = blockIdx.x;
  int tid = threadIdx.x;
  __shared__ float key[9000];
  __shared__ unsigned int win_k[POSTN];
  __shared__ int win_e[POSTN];
  for (int e = tid; e < 9000; e += 64) key[e] = sel_s[(size_t)b * 9000 + e];
  int p0 = 0, p1 = 0;       // frontier ptrs for classes tid and tid+64
  int c1 = tid + 64;        // valid iff c1 < NC (lanes 0..25)
  __syncthreads();
  for (int p = 0; p < POSTN; p++) {
    unsigned long long v = 0ull;
    if (p0 < POSTN) {
      int e = tid * POSTN + p0;
      v = ((unsigned long long)__float_as_uint(key[e]) << 32) |
          (unsigned int)(16383 - e);  // max score, then min flat idx (stable)
    }
    if (c1 < NC && p1 < POSTN) {
      int e = c1 * POSTN + p1;
      unsigned long long v2 = ((unsigned long long)__float_as_uint(key[e]) << 32) |
                              (unsigned int)(16383 - e);
      if (v2 > v) v = v2;
    }
#pragma unroll
    for (int d = 1; d < 64; d <<= 1) {
      unsigned long long o = __shfl_xor(v, d, 64);
      if (o > v) v = o;
    }
    int e = 16383 - (int)(v & 0x3FFFull);
    if (tid == 0) { win_k[p] = (unsigned int)(v >> 32); win_e[p] = e; }
    int cls = e / POSTN;
    int pp = e - cls * POSTN;
    if (cls == tid) p0 = pp + 1;
    else if (cls == c1) p1 = pp + 1;
  }
  __syncthreads();
  for (int p = tid; p < POSTN; p += 64) {
    unsigned int k = win_k[p];
    int e = win_e[p];
    float4 bx = sel_b[(size_t)b * 9000 + e];
    ((float4*)out)[b * POSTN + p] = bx;              // out_b [8,100,4]
    out[3200 + b * POSTN + p] = __uint_as_float(k);  // out_s [8,100]
    out[4000 + b * POSTN + p] = (float)(e / POSTN);  // out_c [8,100]
  }
  int vcnt = 0;
  for (int p = tid; p < POSTN; p += 64) vcnt += (win_k[p] != 0u) ? 1 : 0;
#pragma unroll
  for (int d = 1; d < 64; d <<= 1) vcnt += __shfl_xor(vcnt, d, 64);
  if (tid == 0) out[4800 + b] = (float)vcnt;  // valid [8]
}

// ------------------------------- launcher --------------------------------------

extern "C" void kernel_launch(void* const* d_in, const int* in_sizes, int n_in,
                              void* d_out, int out_size, void* d_ws, size_t ws_size,
                              hipStream_t stream) {
  const float* deltas = (const float*)d_in[0];  // [8,49104,4]
  const float* logits = (const float*)d_in[1];  // [8,49104,90]
  float* out = (float*)d_out;
  char* ws = (char*)d_ws;

  size_t off = 0;
  auto take = [&](size_t bytes) -> char* {
    char* p = ws + off;
    off += (bytes + 255) & ~(size_t)255;
    return p;
  };
  // small/required buffers first so the degraded path fits in ~8.6 MB
  float4* anchors = (float4*)take((size_t)NANCH * 16);
  float4* boxes = (float4*)take((size_t)NB * NANCH * 16);
  float* sel_s = (float*)take((size_t)NBC * POSTN * 4);
  float4* sel_b = (float4*)take((size_t)NBC * POSTN * 16);
  int* flags = (int*)take((size_t)NBC * 4);
  unsigned int* gcnt = (unsigned int*)take((size_t)NBC * 4);
  unsigned int* oflow = (unsigned int*)take((size_t)NBC * 4);
  unsigned long long* gcand =
      (unsigned long long*)take((size_t)NBC * T1CAP * 8);
  bool fits = (off <= ws_size);  // total ~11.5 MB

  k_anchors<<<dim3((NANCH + 255) / 256), dim3(256), 0, stream>>>(anchors, gcnt,
                                                                 oflow);
  k_decode<<<dim3((NB * NANCH + 255) / 256), dim3(256), 0, stream>>>(
      (const float4*)deltas, anchors, boxes);
  if (fits) {
    k_scan<<<dim3(NCH, NB), dim3(256), 0, stream>>>((const float4*)logits,
                                                    gcand, gcnt, oflow);
    k_nms_t1<<<dim3(NBC), dim3(256), 0, stream>>>(gcand, gcnt, oflow, boxes,
                                                  sel_s, sel_b, flags);
  } else {
    k_flagall<<<dim3((NBC + 255) / 256), dim3(256), 0, stream>>>(flags);
  }
  k_nms_fb<8192, 5000><<<dim3(NBC), dim3(256), 0, stream>>>(logits, boxes,
                                                            sel_s, sel_b, flags);
  k_final<<<dim3(NB), dim3(64), 0, stream>>>(sel_s, sel_b, out);
}